// Round 5
// baseline (86.518 us; speedup 1.0000x reference)
//
#include <hip/hip_runtime.h>
#include <hip/hip_bf16.h>

#define NVID 256
#define DIM 1024

typedef short bf16x8 __attribute__((ext_vector_type(8)));
typedef float f32x4 __attribute__((ext_vector_type(4)));

__device__ inline void acc4(float4& a, const float4& v) {
    a.x += v.x; a.y += v.y; a.z += v.z; a.w += v.w;
}

__device__ inline unsigned short f2bf(float f) {
    __hip_bfloat16 h = __float2bfloat16(f);   // RNE
    unsigned short u;
    __builtin_memcpy(&u, &h, 2);
    return u;
}

__device__ inline float bf2f(unsigned short u) {
    return __uint_as_float(((unsigned)u) << 16);
}

// 8-deep unrolled segmented row-mean over a 512-col slice (n >= 8 guaranteed).
// src points at the first row of the segment, already offset to the col slice.
__device__ inline float4 mean_rows_half(const float* __restrict__ src, int n, int t) {
    const float4* srcv = (const float4*)src + t;           // row stride DIM/4 float4s
    float4 a0 = {0,0,0,0}, a1 = {0,0,0,0}, a2 = {0,0,0,0}, a3 = {0,0,0,0};
    int r = 0;
    for (; r + 8 <= n; r += 8) {
        float4 v0 = srcv[(size_t)(r + 0) * (DIM / 4)];
        float4 v1 = srcv[(size_t)(r + 1) * (DIM / 4)];
        float4 v2 = srcv[(size_t)(r + 2) * (DIM / 4)];
        float4 v3 = srcv[(size_t)(r + 3) * (DIM / 4)];
        float4 v4 = srcv[(size_t)(r + 4) * (DIM / 4)];
        float4 v5 = srcv[(size_t)(r + 5) * (DIM / 4)];
        float4 v6 = srcv[(size_t)(r + 6) * (DIM / 4)];
        float4 v7 = srcv[(size_t)(r + 7) * (DIM / 4)];
        acc4(a0, v0); acc4(a1, v1); acc4(a2, v2); acc4(a3, v3);
        acc4(a0, v4); acc4(a1, v5); acc4(a2, v6); acc4(a3, v7);
    }
    for (; r < n; ++r) acc4(a0, srcv[(size_t)r * (DIM / 4)]);
    acc4(a0, a1); acc4(a2, a3); acc4(a0, a2);
    const float inv = 1.0f / (float)n;
    a0.x *= inv; a0.y *= inv; a0.z *= inv; a0.w *= inv;
    return a0;
}

// ---------------------------------------------------------------------------
// K1: 512 blocks x 128 threads. Block b: video vid = b&255, column half
// half = b>>8 (512 cols). Each block computes clip-mean AND cap-mean over
// its col slice (bf16 out) + partial diag -> diagp[half][vid] (no atomics).
// 2x task granularity vs R4 -> HW backfill compresses the imbalance tail.
// Offsets via packed masked reduction (nclip | ncap<<16), not a serial loop.
// ---------------------------------------------------------------------------
__global__ __launch_bounds__(128) void mean_diag_kernel(
    const float* __restrict__ im, const float* __restrict__ s,
    const int* __restrict__ num_clips, const int* __restrict__ num_caps,
    unsigned short* __restrict__ Ab, unsigned short* __restrict__ Bb,
    float* __restrict__ diagp, float* __restrict__ out)
{
    const int b = blockIdx.x;
    const int t = threadIdx.x;          // 0..127
    const int vid = b & (NVID - 1);
    const int half = b >> 8;            // 0 or 1
    if (b == 0 && t == 0) out[0] = 0.0f;

    // packed masked offset reduction: sum over k < vid of (nclip[k] | ncap[k]<<16)
    // thread t covers k = t and k = t+128.
    int psum = 0;
    {
        int k0 = t, k1 = t + 128;
        int v0 = num_clips[k0] | (num_caps[k0] << 16);
        int v1 = num_clips[k1] | (num_caps[k1] << 16);
        if (k0 < vid) psum += v0;
        if (k1 < vid) psum += v1;
    }
    for (int o = 32; o > 0; o >>= 1) psum += __shfl_down(psum, o, 64);
    __shared__ int wpart[2];
    const int wave = t >> 6, lane = t & 63;
    if (lane == 0) wpart[wave] = psum;
    __syncthreads();
    const int packed = wpart[0] + wpart[1];
    const int offc = packed & 0xFFFF;
    const int offp = (packed >> 16) & 0xFFFF;
    const int nc = num_clips[vid];
    const int np = num_caps[vid];

    const int colBase = half * (DIM / 2);          // 0 or 512 floats

    float4 am = mean_rows_half(im + (size_t)offc * DIM + colBase, nc, t);
    float4 bm = mean_rows_half(s  + (size_t)offp * DIM + colBase, np, t);

    ushort4 ua, ub;
    ua.x = f2bf(am.x); ua.y = f2bf(am.y); ua.z = f2bf(am.z); ua.w = f2bf(am.w);
    ub.x = f2bf(bm.x); ub.y = f2bf(bm.y); ub.z = f2bf(bm.z); ub.w = f2bf(bm.w);
    ((ushort4*)(Ab + (size_t)vid * DIM + colBase))[t] = ua;
    ((ushort4*)(Bb + (size_t)vid * DIM + colBase))[t] = ub;

    // partial diag over this col slice, from bf16-rounded values
    float p = bf2f(ua.x) * bf2f(ub.x) + bf2f(ua.y) * bf2f(ub.y)
            + bf2f(ua.z) * bf2f(ub.z) + bf2f(ua.w) * bf2f(ub.w);
    for (int o = 32; o > 0; o >>= 1) p += __shfl_down(p, o, 64);
    __shared__ float wsum[2];
    if (lane == 0) wsum[wave] = p;
    __syncthreads();
    if (t == 0) diagp[half * NVID + vid] = wsum[0] + wsum[1];
}

// ---------------------------------------------------------------------------
// K3: S = A @ B^T via mfma_f32_16x16x32_bf16, fused hinge + reduce.
// One wave per 16x16 tile; grid 16x16. Fragments straight from global
// (A,B bf16 = 1 MB total -> L2-resident). diag[i] = diagp[0][i]+diagp[1][i].
// ---------------------------------------------------------------------------
__global__ __launch_bounds__(64) void loss_kernel(
    const unsigned short* __restrict__ Ab, const unsigned short* __restrict__ Bb,
    const float* __restrict__ diagp, float* __restrict__ out)
{
    const int lane = threadIdx.x;
    const int i0 = blockIdx.y * 16, j0 = blockIdx.x * 16;
    const int m = lane & 15, q = lane >> 4;

    const unsigned short* Ap = Ab + (size_t)(i0 + m) * DIM + q * 8;
    const unsigned short* Bp = Bb + (size_t)(j0 + m) * DIM + q * 8;

    f32x4 acc = {0.f, 0.f, 0.f, 0.f};
#pragma unroll
    for (int kb = 0; kb < DIM; kb += 32) {
        bf16x8 a = *(const bf16x8*)(Ap + kb);
        bf16x8 b = *(const bf16x8*)(Bp + kb);
        acc = __builtin_amdgcn_mfma_f32_16x16x32_bf16(a, b, acc, 0, 0, 0);
    }

    const int j = j0 + m;
    const float dj = diagp[j] + diagp[NVID + j];
    const float4 di0 = *(const float4*)&diagp[i0 + q * 4];
    const float4 di1 = *(const float4*)&diagp[NVID + i0 + q * 4];
    const float dia[4] = {di0.x + di1.x, di0.y + di1.y, di0.z + di1.z, di0.w + di1.w};

    float v = 0.f;
#pragma unroll
    for (int r = 0; r < 4; ++r) {
        const int i = i0 + q * 4 + r;
        if (i != j) {
            const float sv = acc[r];
            v += fmaxf(sv - dia[r], 0.f) + fmaxf(sv - dj, 0.f);
        }
    }

    for (int o = 32; o > 0; o >>= 1) v += __shfl_down(v, o, 64);
    if (lane == 0) atomicAdd(out, v);
}

// ---------------------------------------------------------------------------
extern "C" void kernel_launch(void* const* d_in, const int* in_sizes, int n_in,
                              void* d_out, int out_size, void* d_ws, size_t ws_size,
                              hipStream_t stream) {
    const float* im    = (const float*)d_in[0];
    const float* s     = (const float*)d_in[1];
    const int*   nclip = (const int*)d_in[2];
    const int*   ncap  = (const int*)d_in[3];
    float* out = (float*)d_out;

    unsigned short* Ab = (unsigned short*)d_ws;       // 512 KB
    unsigned short* Bb = Ab + NVID * DIM;             // 512 KB
    float* diagp = (float*)(Bb + NVID * DIM);         // 2 KB (2 x 256)

    mean_diag_kernel<<<2 * NVID, 128, 0, stream>>>(im, s, nclip, ncap, Ab, Bb, diagp, out);
    loss_kernel<<<dim3(16, 16), 64, 0, stream>>>(Ab, Bb, diagp, out);
}